// Round 5
// baseline (137.314 us; speedup 1.0000x reference)
//
#include <hip/hip_runtime.h>
#include <math.h>

#define D100 100
#define NE 50000
#define BATCH 16
#define EPS_F 1e-5f
#define NPAD 50016            // 50000 -> multiple of 16 (zero-padded)
#define NCH 3126              // NPAD/16 K-chunks
#define CPB 13                // chunks per k2g block
#define NBG 241               // ceil(NCH/CPB)
#define SLICES 16

typedef __attribute__((ext_vector_type(8))) short short8;
typedef __attribute__((ext_vector_type(16))) float float16;
typedef unsigned short u16;

__device__ __forceinline__ u16 f2bf(float x) {   // RNE float->bf16
  union { float f; unsigned u; } c; c.f = x;
  unsigned r = c.u + 0x7FFFu + ((c.u >> 16) & 1u);
  return (u16)(r >> 16);
}
__device__ __forceinline__ float bf2f(u16 v) {
  return __uint_as_float(((unsigned)v) << 16);
}

// ---------------------------------------------------------------------------
// K1 fallback (monolithic)
__global__ void k1_wm(const float* __restrict__ W_re, const float* __restrict__ W_im,
                      const float* __restrict__ R2, const int* __restrict__ r_idx,
                      float* __restrict__ Wm) {
  const int t = blockIdx.y;
  const float* W = t ? W_im : W_re;
  int ef = blockIdx.x * 256 + threadIdx.x;
  if (ef >= 10000) return;
  int ridx[16];
#pragma unroll
  for (int b = 0; b < 16; b++) ridx[b] = r_idx[b];
  float acc[16];
#pragma unroll
  for (int b = 0; b < 16; b++) acc[b] = 0.f;
  for (int k = 0; k < 100; k++) {
    float w = W[k * 10000 + ef];
#pragma unroll
    for (int b = 0; b < 16; b++) acc[b] = fmaf(R2[ridx[b] * 100 + k], w, acc[b]);
  }
  float* o = Wm + t * 160000 + ef;
#pragma unroll
  for (int b = 0; b < 16; b++) o[b * 10000] = acc[b];
}

// K1a: split-K partials. grid (10, 4, 2), block 256
__global__ void k1a_wm(const float* __restrict__ W_re, const float* __restrict__ W_im,
                       const float* __restrict__ R2, const int* __restrict__ r_idx,
                       float* __restrict__ Wm_p) {
  const int t = blockIdx.z, kc = blockIdx.y;
  const float* W = t ? W_im : W_re;
  const float4* W4 = (const float4*)W;
  __shared__ float r2s[16][28];
  const int tid = threadIdx.x;
  for (int i = tid; i < 400; i += 256) {
    int b = i / 25, kk = i - b * 25;
    r2s[b][kk] = R2[r_idx[b] * 100 + kc * 25 + kk];
  }
  __syncthreads();
  int ef4 = blockIdx.x * 256 + tid;
  if (ef4 < 2500) {
    float4 acc[16];
#pragma unroll
    for (int b = 0; b < 16; b++) acc[b] = make_float4(0.f, 0.f, 0.f, 0.f);
#pragma unroll 5
    for (int kk = 0; kk < 25; kk++) {
      float4 w = W4[(kc * 25 + kk) * 2500 + ef4];
#pragma unroll
      for (int b = 0; b < 16; b++) {
        float r = r2s[b][kk];
        acc[b].x = fmaf(r, w.x, acc[b].x);
        acc[b].y = fmaf(r, w.y, acc[b].y);
        acc[b].z = fmaf(r, w.z, acc[b].z);
        acc[b].w = fmaf(r, w.w, acc[b].w);
      }
    }
    float4* o = (float4*)(Wm_p + (long)kc * 320000 + t * 160000);
#pragma unroll
    for (int b = 0; b < 16; b++) o[b * 2500 + ef4] = acc[b];
  }
}

// K1b: Wm = sum over 4 kc partials.  grid (313), block 256
__global__ void k1b_reduce(const float* __restrict__ Wm_p, float* __restrict__ Wm) {
  int i4 = blockIdx.x * 256 + threadIdx.x;
  if (i4 >= 80000) return;
  const float4* P4 = (const float4*)Wm_p;
  float4 a = P4[i4], b = P4[80000 + i4], c = P4[160000 + i4], d = P4[240000 + i4];
  float4 o;
  o.x = a.x + b.x + c.x + d.x;
  o.y = a.y + b.y + c.y + d.y;
  o.z = a.z + b.z + c.z + d.z;
  o.w = a.w + b.w + c.w + d.w;
  ((float4*)Wm)[i4] = o;
}

// ---------------------------------------------------------------------------
// K2t: E (50000x100 f32) -> FR fragment-major bf16.
// FR[t][rb][nc][lane] (16B) = rows rb*32+(lane&31), n = nc*16 + (lane>>5)*8 .. +8
// grid (782, 2), block 256
__global__ __launch_bounds__(256) void k2t_frag(const float* __restrict__ E_a,
                                                const float* __restrict__ E_b,
                                                u16* __restrict__ FR) {
  const int t = blockIdx.y;
  const float4* E4 = (const float4*)(t ? E_b : E_a);
  __shared__ u16 Tl[100][72];       // [e][n_local], pitch 72 keeps rows 16B-aligned
  const int tid = threadIdx.x;
  const int n0 = blockIdx.x * 64;
  for (int i = tid; i < 1600; i += 256) {
    int nl = i / 25, e4 = i - nl * 25;
    float4 v = make_float4(0.f, 0.f, 0.f, 0.f);
    if (n0 + nl < NE) v = E4[(long)(n0 + nl) * 25 + e4];
    Tl[e4 * 4 + 0][nl] = f2bf(v.x);
    Tl[e4 * 4 + 1][nl] = f2bf(v.y);
    Tl[e4 * 4 + 2][nl] = f2bf(v.z);
    Tl[e4 * 4 + 3][nl] = f2bf(v.w);
  }
  __syncthreads();
  u16* out = FR + (long)t * 4 * NCH * 512;
  const short8 z8 = {0, 0, 0, 0, 0, 0, 0, 0};
  for (int i = tid; i < 1024; i += 256) {
    int chunk = i >> 6, lane = i & 63;
    int rb = chunk >> 2, ncl = chunk & 3;
    int nc = blockIdx.x * 4 + ncl;
    if (nc >= NCH) continue;
    int row = rb * 32 + (lane & 31);
    int nloc = ncl * 16 + ((lane >> 5) << 3);
    short8 v = (row < 100) ? *(const short8*)&Tl[row][nloc] : z8;
    *(short8*)(out + ((long)(rb * NCH + nc)) * 512 + lane * 8) = v;
  }
}

// ---------------------------------------------------------------------------
// K2g: MFMA Gram partials from FR.  grid (NBG, 2), block 256 (4 waves).
// All loads are 1KB contiguous per wave (fragment-major), no LDS.
__global__ __launch_bounds__(256) void k2g_mfma(const u16* __restrict__ FR,
                                                float* __restrict__ Gp,
                                                float* __restrict__ CSp) {
  const int t = blockIdx.y, bx = blockIdx.x;
  const int tid = threadIdx.x, wave = tid >> 6, lane = tid & 63;
  const int l31 = lane & 31;
  const int nc0 = bx * CPB;
  const int ncend = min(nc0 + CPB, NCH);
  const u16* base = FR + (long)t * 4 * NCH * 512 + lane * 8;
  const u16* q0 = base + ((long)(0 * NCH + nc0)) * 512;
  const u16* q1 = base + ((long)(1 * NCH + nc0)) * 512;
  const u16* q2 = base + ((long)(2 * NCH + nc0)) * 512;
  const u16* q3 = base + ((long)(3 * NCH + nc0)) * 512;
  const u16* qa = base + ((long)(wave * NCH + nc0)) * 512;
  float16 acc0, acc1, acc2, acc3;
#pragma unroll 16
  for (int r = 0; r < 16; r++) { acc0[r] = 0.f; acc1[r] = 0.f; acc2[r] = 0.f; acc3[r] = 0.f; }
  float cs = 0.f;

  for (int nc = nc0; nc < ncend; nc++) {
    short8 f0 = *(const short8*)q0; q0 += 512;
    short8 f1 = *(const short8*)q1; q1 += 512;
    short8 f2 = *(const short8*)q2; q2 += 512;
    short8 f3 = *(const short8*)q3; q3 += 512;
    short8 a  = *(const short8*)qa; qa += 512;
    acc0 = __builtin_amdgcn_mfma_f32_32x32x16_bf16(a, f0, acc0, 0, 0, 0);
    acc1 = __builtin_amdgcn_mfma_f32_32x32x16_bf16(a, f1, acc1, 0, 0, 0);
    acc2 = __builtin_amdgcn_mfma_f32_32x32x16_bf16(a, f2, acc2, 0, 0, 0);
    acc3 = __builtin_amdgcn_mfma_f32_32x32x16_bf16(a, f3, acc3, 0, 0, 0);
#pragma unroll 8
    for (int j = 0; j < 8; j++) cs += bf2f((u16)a[j]);   // colsum, co-issues on VALU
  }

  float* gp = Gp + ((long)t * NBG + bx) * 10000;
#pragma unroll 16
  for (int r = 0; r < 16; r++) {
    int m = (r & 3) + 8 * (r >> 2) + 4 * (lane >> 5);    // verified C/D mapping
    int e = wave * 32 + m;
    if (e < 100) {
      gp[e * 100 + l31] = acc0[r];
      gp[e * 100 + 32 + l31] = acc1[r];
      gp[e * 100 + 64 + l31] = acc2[r];
      if (l31 < 4) gp[e * 100 + 96 + l31] = acc3[r];
    }
  }
  cs += __shfl_xor(cs, 32);
  int row = wave * 32 + l31;
  if (lane < 32 && row < 100)
    CSp[((long)t * NBG + bx) * 100 + row] = cs;
}

// ---------------------------------------------------------------------------
// K2 fallback: VALU Gram (only if workspace too small for FR)
__global__ __launch_bounds__(256, 4) void k2_gram(const float* __restrict__ E_a,
                                                  const float* __restrict__ E_b,
                                                  float* __restrict__ Gp,
                                                  float* __restrict__ CSp,
                                                  int NB, int RPB) {
  const int t = blockIdx.y;
  const float* E = t ? E_b : E_a;
  const float4* E4 = (const float4*)E;
  __shared__ float sm[32][128];
  const int tid = threadIdx.x;
  const int bx = blockIdx.x;
  int r0 = bx * RPB;
  int rend = min(r0 + RPB, NE);
  for (int i = tid; i < 32 * 28; i += 256) {
    int r = i / 28;
    sm[r][100 + (i - r * 28)] = 0.f;
  }
  float acc[8][8];
#pragma unroll
  for (int i = 0; i < 8; i++)
#pragma unroll
    for (int j = 0; j < 8; j++) acc[i][j] = 0.f;
  float cs = 0.f;
  const int ty = tid >> 4, tx = tid & 15;
  for (int base = r0; base < rend; base += 32) {
    int cnt = min(32, rend - base);
    __syncthreads();
    for (int i = tid; i < 800; i += 256) {
      int r = i / 25, c4 = i - r * 25;
      float4 v = make_float4(0.f, 0.f, 0.f, 0.f);
      if (r < cnt) v = E4[(long)(base + r) * 25 + c4];
      *(float4*)&sm[r][c4 * 4] = v;
    }
    __syncthreads();
#pragma unroll 2
    for (int r = 0; r < 32; r++) {
      float4 a0 = *(const float4*)&sm[r][ty * 8];
      float4 a1 = *(const float4*)&sm[r][ty * 8 + 4];
      float4 b0 = *(const float4*)&sm[r][tx * 8];
      float4 b1 = *(const float4*)&sm[r][tx * 8 + 4];
      float av[8] = {a0.x, a0.y, a0.z, a0.w, a1.x, a1.y, a1.z, a1.w};
      float bv[8] = {b0.x, b0.y, b0.z, b0.w, b1.x, b1.y, b1.z, b1.w};
#pragma unroll
      for (int i = 0; i < 8; i++)
#pragma unroll
        for (int j = 0; j < 8; j++) acc[i][j] = fmaf(av[i], bv[j], acc[i][j]);
    }
    if (tid < 100) {
#pragma unroll 4
      for (int r = 0; r < 32; r++) cs += sm[r][tid];
    }
  }
  float* gp = Gp + ((long)t * NB + bx) * 10000;
#pragma unroll
  for (int i = 0; i < 8; i++) {
    int e = ty * 8 + i;
    if (e < 100) {
#pragma unroll
      for (int j = 0; j < 8; j++) {
        int ep = tx * 8 + j;
        if (ep < 100) gp[e * 100 + ep] = acc[i][j];
      }
    }
  }
  if (tid < 100) CSp[((long)t * NB + bx) * 100 + tid] = cs;
}

// ---------------------------------------------------------------------------
// K3a/K3b: tree reduce of Gram + colsum partials
__global__ void k3a_reduce(const float* __restrict__ Gp, const float* __restrict__ CSp,
                           float* __restrict__ Gp2, float* __restrict__ CSp2,
                           int NB, int seg) {
  int chunk = blockIdx.x, slice = blockIdx.y, t = blockIdx.z;
  int nb0 = slice * seg;
  int nb1 = min(nb0 + seg, NB);
  int idx = chunk * 256 + threadIdx.x;
  if (idx < 10000) {
    float s = 0.f;
    const float* p = Gp + ((long)t * NB + nb0) * 10000 + idx;
    for (int nb = nb0; nb < nb1; nb++, p += 10000) s += *p;
    Gp2[(t * SLICES + slice) * 10000 + idx] = s;
  }
  if (chunk == 0 && threadIdx.x < 100) {
    float s = 0.f;
    const float* p = CSp + ((long)t * NB + nb0) * 100 + threadIdx.x;
    for (int nb = nb0; nb < nb1; nb++, p += 100) s += *p;
    CSp2[(t * SLICES + slice) * 100 + threadIdx.x] = s;
  }
}

__global__ void k3b_reduce(const float* __restrict__ Gp2, const float* __restrict__ CSp2,
                           float* __restrict__ G, float* __restrict__ CS) {
  int chunk = blockIdx.x, t = blockIdx.y;
  int idx = chunk * 256 + threadIdx.x;
  if (idx < 10000) {
    float s = 0.f;
    const float* p = Gp2 + (long)t * SLICES * 10000 + idx;
#pragma unroll
    for (int sl = 0; sl < SLICES; sl++) s += p[sl * 10000];
    G[t * 10000 + idx] = s;
  }
  if (chunk == 0 && threadIdx.x < 100) {
    float s = 0.f;
    const float* p = CSp2 + (long)t * SLICES * 100 + threadIdx.x;
#pragma unroll
    for (int sl = 0; sl < SLICES; sl++) s += p[sl * 100];
    CS[t * 100 + threadIdx.x] = s;
  }
}

// ---------------------------------------------------------------------------
// K4: gather h, BN2, matvec -> traw.  grid (16), block 256
__global__ void k4_core1(const float* __restrict__ E_a, const float* __restrict__ E_b,
                         const int* __restrict__ h_idx, const float* __restrict__ Wm,
                         const float* __restrict__ g0r, const float* __restrict__ b0r,
                         const float* __restrict__ g0i, const float* __restrict__ b0i,
                         float* __restrict__ traw) {
  __shared__ float ha[1600], hb[1600], xa[100], xb[100];
  int tid = threadIdx.x, bo = blockIdx.x;
  for (int idx = tid; idx < 1600; idx += 256) {
    int bb = idx / 100, e = idx - bb * 100;
    int h = h_idx[bb];
    ha[idx] = E_a[h * 100 + e];
    hb[idx] = E_b[h * 100 + e];
  }
  __syncthreads();
  if (tid < 100) {
    float m = 0.f, s = 0.f;
#pragma unroll
    for (int b = 0; b < 16; b++) { float v = ha[b * 100 + tid]; m += v; s += v * v; }
    m *= (1.f / 16.f);
    float var = s * (1.f / 16.f) - m * m;
    xa[tid] = (ha[bo * 100 + tid] - m) * rsqrtf(var + EPS_F) * g0r[tid] + b0r[tid];
    m = 0.f; s = 0.f;
#pragma unroll
    for (int b = 0; b < 16; b++) { float v = hb[b * 100 + tid]; m += v; s += v * v; }
    m *= (1.f / 16.f);
    var = s * (1.f / 16.f) - m * m;
    xb[tid] = (hb[bo * 100 + tid] - m) * rsqrtf(var + EPS_F) * g0i[tid] + b0i[tid];
  }
  __syncthreads();
  if (tid < 100) {
    float sa = 0.f, sb = 0.f;
    const float* wa = Wm + bo * 10000 + tid;
    const float* wb = Wm + 160000 + bo * 10000 + tid;
    for (int e = 0; e < 100; e++) {
      sa = fmaf(xa[e], wa[e * 100], sa);
      sb = fmaf(xb[e], wb[e * 100], sb);
    }
    traw[bo * 100 + tid] = sa;
    traw[1600 + bo * 100 + tid] = sb;
  }
}

// ---------------------------------------------------------------------------
// K5: BN2 of traw + Mobius -> t0,t1.  grid(1), block 256
__global__ void k5_core2(const float* __restrict__ traw,
                         const float* __restrict__ R_re, const float* __restrict__ R_im,
                         const int* __restrict__ r_idx,
                         const float* __restrict__ g1r, const float* __restrict__ b1r,
                         const float* __restrict__ g1i, const float* __restrict__ b1i,
                         float* __restrict__ t01) {
  __shared__ float ta[1600], tb[1600], sca[100], sha[100], scb[100], shb[100];
  int tid = threadIdx.x;
  for (int i = tid; i < 1600; i += 256) { ta[i] = traw[i]; tb[i] = traw[1600 + i]; }
  __syncthreads();
  if (tid < 100) {
    float m = 0.f, s = 0.f;
#pragma unroll
    for (int b = 0; b < 16; b++) { float v = ta[b * 100 + tid]; m += v; s += v * v; }
    m *= (1.f / 16.f);
    float var = s * (1.f / 16.f) - m * m;
    float sc = rsqrtf(var + EPS_F) * g1r[tid];
    sca[tid] = sc; sha[tid] = b1r[tid] - m * sc;
    m = 0.f; s = 0.f;
#pragma unroll
    for (int b = 0; b < 16; b++) { float v = tb[b * 100 + tid]; m += v; s += v * v; }
    m *= (1.f / 16.f);
    var = s * (1.f / 16.f) - m * m;
    sc = rsqrtf(var + EPS_F) * g1i[tid];
    scb[tid] = sc; shb[tid] = b1i[tid] - m * sc;
  }
  __syncthreads();
  for (int idx = tid; idx < 1600; idx += 256) {
    int b = idx / 100, f = idx - b * 100;
    float va = ta[idx] * sca[f] + sha[f];
    float vb = tb[idx] * scb[f] + shb[f];
    int base = r_idx[b] * 400 + f;
    float ra0 = R_re[base],       ra1 = R_im[base];
    float rb0 = R_re[base + 100], rb1 = R_im[base + 100];
    float rc0 = R_re[base + 200], rc1 = R_im[base + 200];
    float rd0 = R_re[base + 300], rd1 = R_im[base + 300];
    float top0 = va * ra0 - vb * ra1 + rb0;
    float top1 = va * ra1 + vb * ra0 + rb1;
    float bot0 = va * rc0 - vb * rc1 + rd0;
    float bot1 = va * rc1 + vb * rc0 + rd1;
    float den = bot0 * bot0 + bot1 * bot1;
    t01[idx]        = (top0 * bot0 + top1 * bot1) / den;
    t01[1600 + idx] = (top1 * bot0 - top0 * bot1) / den;
  }
}

// ---------------------------------------------------------------------------
// K6p: fused k6+k7 partial stats. grid (4, 16, 2), block 256.
// s1p[t][b][c][f] = sum_{ep in chunk} (sum_e G[e][ep] Wm[e][f]) * Wm[ep][f]
// s2p[t][b][f]    = sum_e Wm[e][f] * CS[e]        (chunk 0 only)
__global__ __launch_bounds__(256) void k6p_stats(const float* __restrict__ Wm,
                                                 const float* __restrict__ G,
                                                 const float* __restrict__ CS,
                                                 float* __restrict__ s1p,
                                                 float* __restrict__ s2p) {
  int c = blockIdx.x, b = blockIdx.y, t = blockIdx.z;
  int tid = threadIdx.x;
  __shared__ float Gl[100][25];
  __shared__ float CSl[100];
  __shared__ float s1l[2][128];
  for (int i = tid; i < 2500; i += 256) {
    int e = i / 25, epl = i - e * 25;
    Gl[e][epl] = G[t * 10000 + e * 100 + c * 25 + epl];
  }
  if (tid < 100) CSl[tid] = CS[t * 100 + tid];
  __syncthreads();
  int f = tid & 127, half = tid >> 7;
  const float* Wb = Wm + t * 160000 + b * 10000;
  float s1 = 0.f;
  if (f < 100) {
    int ep0 = half ? 13 : 0;
    int ne = half ? 12 : 13;
    float a[13];
#pragma unroll
    for (int k = 0; k < 13; k++) a[k] = 0.f;
    for (int e = 0; e < 100; e++) {
      float wv = Wb[e * 100 + f];
#pragma unroll
      for (int k = 0; k < 13; k++)
        if (k < ne) a[k] = fmaf(Gl[e][ep0 + k], wv, a[k]);
    }
#pragma unroll
    for (int k = 0; k < 13; k++)
      if (k < ne) s1 += a[k] * Wb[(c * 25 + ep0 + k) * 100 + f];
  }
  s1l[half][f] = (f < 100) ? s1 : 0.f;
  __syncthreads();
  if (tid < 100)
    s1p[((t * 16 + b) * 4 + c) * 100 + tid] = s1l[0][tid] + s1l[1][tid];
  if (c == 0 && half == 0 && f < 100) {
    float s2 = 0.f;
    for (int e = 0; e < 100; e++) s2 = fmaf(Wb[e * 100 + f], CSl[e], s2);
    s2p[(t * 16 + b) * 100 + f] = s2;
  }
}

// ---------------------------------------------------------------------------
// K8: finalize alpha/beta from partials, then u, c.  grid (16), block 128
__global__ void k8_u(const float* __restrict__ t01,
                     const float* __restrict__ s1p, const float* __restrict__ s2p,
                     const float* __restrict__ gEa, const float* __restrict__ bEa,
                     const float* __restrict__ gEb, const float* __restrict__ bEb,
                     const float* __restrict__ Wm,
                     float* __restrict__ u, float* __restrict__ c) {
  int b = blockIdx.x, tid = threadIdx.x;
  __shared__ float al[2][100], be[2][100];
  __shared__ float w0[100], w1[100], pc[128];
  if (tid < 100) {
#pragma unroll 2
    for (int t = 0; t < 2; t++) {
      float s1 = 0.f;
      for (int q = 0; q < 64; q++) s1 += s1p[t * 6400 + q * 100 + tid];
      float s2 = 0.f;
      for (int b2 = 0; b2 < 16; b2++) s2 += s2p[t * 1600 + b2 * 100 + tid];
      float mean = s2 * (1.f / 800000.f);
      float var = s1 * (1.f / 800000.f) - mean * mean;
      float g = t ? gEb[tid] : gEa[tid];
      float bb = t ? bEb[tid] : bEa[tid];
      float a = rsqrtf(var + EPS_F) * g;
      al[t][tid] = a;
      be[t][tid] = bb - mean * a;
    }
  }
  __syncthreads();
  float p = 0.f;
  if (tid < 100) {
    float t0 = t01[b * 100 + tid], t1 = t01[1600 + b * 100 + tid];
    w0[tid] = t0 * al[0][tid];
    w1[tid] = t1 * al[1][tid];
    p = t0 * be[0][tid] + t1 * be[1][tid];
  }
  pc[tid] = (tid < 100) ? p : 0.f;
  __syncthreads();
  for (int o = 64; o > 0; o >>= 1) {
    if (tid < o) pc[tid] += pc[tid + o];
    __syncthreads();
  }
  if (tid == 0) c[b] = pc[0];
  if (tid < 100) {
    float sa = 0.f, sb = 0.f;
    const float* wa = Wm + b * 10000 + tid * 100;
    const float* wb = Wm + 160000 + b * 10000 + tid * 100;
    for (int f = 0; f < 100; f++) {
      sa = fmaf(w0[f], wa[f], sa);
      sb = fmaf(w1[f], wb[f], sb);
    }
    u[tid * 16 + b] = sa;
    u[(100 + tid) * 16 + b] = sb;
  }
}

// ---------------------------------------------------------------------------
// K9: score = sigmoid(c + u_a·E_a + u_b·E_b).  grid (196), block 256
__device__ __forceinline__ float f4get(const float4& v, int j) {
  switch (j) { case 0: return v.x; case 1: return v.y; case 2: return v.z; default: return v.w; }
}

__global__ __launch_bounds__(256) void k9_score(const float* __restrict__ E_a,
                                                const float* __restrict__ E_b,
                                                const float* __restrict__ u,
                                                const float* __restrict__ c,
                                                float* __restrict__ out) {
  int n = blockIdx.x * 256 + threadIdx.x;
  if (n >= NE) return;
  const float4* Ea4 = (const float4*)E_a;
  const float4* Eb4 = (const float4*)E_b;
  float acc[16];
#pragma unroll
  for (int b = 0; b < 16; b++) acc[b] = 0.f;
  for (int e4 = 0; e4 < 25; e4++) {
    float4 va = Ea4[n * 25 + e4];
    float4 vb = Eb4[n * 25 + e4];
    const float* ua = u + e4 * 64;
    const float* ub = u + 1600 + e4 * 64;
#pragma unroll
    for (int j = 0; j < 4; j++) {
      float fa = f4get(va, j);
      float fb = f4get(vb, j);
#pragma unroll
      for (int b = 0; b < 16; b++) {
        acc[b] = fmaf(ua[j * 16 + b], fa, acc[b]);
        acc[b] = fmaf(ub[j * 16 + b], fb, acc[b]);
      }
    }
  }
#pragma unroll
  for (int b = 0; b < 16; b++) {
    float x = acc[b] + c[b];
    out[b * NE + n] = 1.f / (1.f + expf(-x));
  }
}

// ---------------------------------------------------------------------------
extern "C" void kernel_launch(void* const* d_in, const int* in_sizes, int n_in,
                              void* d_out, int out_size, void* d_ws, size_t ws_size,
                              hipStream_t stream) {
  const int* h_idx = (const int*)d_in[0];
  const int* r_idx = (const int*)d_in[1];
  const float* E_a = (const float*)d_in[2];
  const float* E_b = (const float*)d_in[3];
  const float* R_re = (const float*)d_in[4];
  const float* R_im = (const float*)d_in[5];
  const float* R2 = (const float*)d_in[6];
  const float* W_re = (const float*)d_in[7];
  const float* W_im = (const float*)d_in[8];
  const float* g0r = (const float*)d_in[9];
  const float* b0r = (const float*)d_in[10];
  const float* g1r = (const float*)d_in[11];
  const float* b1r = (const float*)d_in[12];
  const float* g0i = (const float*)d_in[13];
  const float* b0i = (const float*)d_in[14];
  const float* g1i = (const float*)d_in[15];
  const float* b1i = (const float*)d_in[16];
  const float* gEa = (const float*)d_in[17];
  const float* bEa = (const float*)d_in[18];
  const float* gEb = (const float*)d_in[19];
  const float* bEb = (const float*)d_in[20];
  float* out = (float*)d_out;
  float* ws = (float*)d_ws;

  // fixed regions (365,816 floats)
  float* Wm = ws;                    // [2][16][10000]   320000
  float* G = Wm + 320000;            // [2][10000]        20000
  float* CS = G + 20000;             // [2][100]            200
  float* traw = CS + 200;            // [2][16][100]       3200
  float* t01 = traw + 3200;          // [2][16][100]       3200
  float* u = t01 + 3200;             // [2][100][16]       3200
  float* c = u + 3200;               //                      16
  float* s1p = c + 16;               // [2][16][4][100]   12800
  float* s2p = s1p + 12800;          // [2][16][100]       3200
  const long fixed = 365816;

  float* un = ws + fixed;
  long avail = (long)(ws_size / 4);
  long unionFloats = avail - fixed - 64;

  // k1 scratch overlaps the union head (lifetime ends before k2t)
  float* Wm_p = un;                  // 1,280,000 floats
  int splitK1 = (unionFloats >= 1280000);
  if (splitK1) {
    hipLaunchKernelGGL(k1a_wm, dim3(10, 4, 2), dim3(256), 0, stream, W_re, W_im, R2, r_idx, Wm_p);
    hipLaunchKernelGGL(k1b_reduce, dim3(313), dim3(256), 0, stream, Wm_p, Wm);
  } else {
    hipLaunchKernelGGL(k1_wm, dim3(40, 2), dim3(256), 0, stream, W_re, W_im, R2, r_idx, Wm);
  }

  const long frFloats = (2L * 4 * NCH * 512) / 2;   // 6,402,048
  const long needMain = frFloats + 323200 + (long)NBG * 20200;  // FR + Gp2/CSp2 + Gp/CSp
  if (unionFloats >= needMain) {
    // ---- MFMA Gram path (fragment-major) ----
    u16* FR = (u16*)un;
    float* Gp2 = un + frFloats;
    float* CSp2 = Gp2 + 320000;
    float* Gp = CSp2 + 3200;
    float* CSp = Gp + (long)NBG * 20000;
    int seg = (NBG + SLICES - 1) / SLICES;
    hipLaunchKernelGGL(k2t_frag, dim3(782, 2), dim3(256), 0, stream, E_a, E_b, FR);
    hipLaunchKernelGGL(k2g_mfma, dim3(NBG, 2), dim3(256), 0, stream, FR, Gp, CSp);
    hipLaunchKernelGGL(k3a_reduce, dim3(40, SLICES, 2), dim3(256), 0, stream,
                       Gp, CSp, Gp2, CSp2, NBG, seg);
    hipLaunchKernelGGL(k3b_reduce, dim3(40, 2), dim3(256), 0, stream, Gp2, CSp2, G, CS);
  } else {
    // ---- fallback VALU Gram path ----
    float* Gp2 = un;
    float* CSp2 = Gp2 + 320000;
    float* Gp = CSp2 + 3200;
    long room = (unionFloats - 323200) / 20200;
    int NB = room < 360 ? (int)room : 360;
    if (NB < 1) NB = 1;
    int RPB = (NE + NB - 1) / NB;
    int seg = (NB + SLICES - 1) / SLICES;
    float* CSp = Gp + (long)NB * 20000;
    hipLaunchKernelGGL(k2_gram, dim3(NB, 2), dim3(256), 0, stream, E_a, E_b, Gp, CSp, NB, RPB);
    hipLaunchKernelGGL(k3a_reduce, dim3(40, SLICES, 2), dim3(256), 0, stream,
                       Gp, CSp, Gp2, CSp2, NB, seg);
    hipLaunchKernelGGL(k3b_reduce, dim3(40, 2), dim3(256), 0, stream, Gp2, CSp2, G, CS);
  }

  hipLaunchKernelGGL(k4_core1, dim3(16), dim3(256), 0, stream, E_a, E_b, h_idx, Wm,
                     g0r, b0r, g0i, b0i, traw);
  hipLaunchKernelGGL(k5_core2, dim3(1), dim3(256), 0, stream, traw, R_re, R_im, r_idx,
                     g1r, b1r, g1i, b1i, t01);
  hipLaunchKernelGGL(k6p_stats, dim3(4, 16, 2), dim3(256), 0, stream, Wm, G, CS, s1p, s2p);
  hipLaunchKernelGGL(k8_u, dim3(16), dim3(128), 0, stream, t01, s1p, s2p,
                     gEa, bEa, gEb, bEb, Wm, u, c);
  hipLaunchKernelGGL(k9_score, dim3((NE + 255) / 256), dim3(256), 0, stream,
                     E_a, E_b, u, c, out);
}